// Round 8
// baseline (385.414 us; speedup 1.0000x reference)
//
#include <hip/hip_runtime.h>
#include <math.h>

#define NBOX 1024
#define PI_F 3.141592653f
#define TWO_PI_F 6.283185306f
#define HALF_PI_F 1.5707963265f
#define IOU_THR_F 0.3f

__device__ __forceinline__ float limit_period_f(float v) {
    return v - floorf(v / TWO_PI_F + 0.5f) * TWO_PI_F;
}

// ---------------------------------------------------------------------------
// Clip polygon (px,py,cnt) by half-plane left of edge (a->b).
// Fully unrolled, register-only (no runtime-indexed array writes).
// ---------------------------------------------------------------------------
__device__ __forceinline__ void clip_edge(float (&px)[8], float (&py)[8], int &cnt,
                                          float axp, float ayp, float bxp, float byp) {
    float ex = bxp - axp, ey = byp - ayp;
    float d[8];
#pragma unroll
    for (int v = 0; v < 8; ++v)
        d[v] = ex * (py[v] - ayp) - ey * (px[v] - axp);

    float cxv[16], cyv[16];
    bool fl[16];
#pragma unroll
    for (int v = 0; v < 8; ++v) {
        bool valid = v < cnt;
        bool wrap = !(v + 1 < cnt);              // reference: nxt = idx+1<cnt ? idx+1 : 0
        float p2x = wrap ? px[0] : px[(v + 1) & 7];
        float p2y = wrap ? py[0] : py[(v + 1) & 7];
        float d2v = wrap ? d[0] : d[(v + 1) & 7];
        float d1v = d[v];
        bool in1 = d1v >= 0.0f, in2 = d2v >= 0.0f;
        fl[2 * v] = in1 && valid;
        cxv[2 * v] = px[v];
        cyv[2 * v] = py[v];
        fl[2 * v + 1] = (in1 != in2) && valid;
        float den = d1v - d2v;
        float t = d1v / (fabsf(den) > 1e-8f ? den : 1.0f);
        cxv[2 * v + 1] = px[v] + t * (p2x - px[v]);
        cyv[2 * v + 1] = py[v] + t * (p2y - py[v]);
    }

    // Compact candidates into output slots with an unrolled select network.
    int pos = 0;
    float ox[8], oy[8];
#pragma unroll
    for (int o = 0; o < 8; ++o) { ox[o] = 0.0f; oy[o] = 0.0f; }
#pragma unroll
    for (int c = 0; c < 16; ++c) {
#pragma unroll
        for (int o = 0; o < 8; ++o) {
            if (o > c) continue;                 // pos[c] <= c, compile-time prune
            if (fl[c] && pos == o) { ox[o] = cxv[c]; oy[o] = cyv[c]; }
        }
        pos += fl[c] ? 1 : 0;
    }
    cnt = pos > 8 ? 8 : pos;
#pragma unroll
    for (int v = 0; v < 8; ++v) { px[v] = ox[v]; py[v] = oy[v]; }
}

// ---------------------------------------------------------------------------
// Kernel 1: pairwise IoU3D > 0.3 adjacency bitmask. One thread per (i,j);
// wave = 64 consecutive j for one i -> one u64 adjacency word per wave.
// Natural layout: adj[i*16 + g] bit l = adjacency(i, 64g + l).
// ---------------------------------------------------------------------------
__global__ __launch_bounds__(256) void iou_adj_kernel(const float* __restrict__ boxes,
                                                      unsigned long long* __restrict__ adj) {
    int t = blockIdx.x * 256 + threadIdx.x;
    int i = t >> 10;
    int j = t & 1023;
    const float* ba = boxes + i * 7;
    const float* bb = boxes + j * 7;
    float ax = ba[0], ay = ba[1], az = ba[2], al = ba[3], aw = ba[4], ah = ba[5];
    float bx = bb[0], by = bb[1], bz = bb[2], bl = bb[3], bw = bb[4], bh = bb[5];
    float tha = limit_period_f(ba[6]);
    float thb = limit_period_f(bb[6]);

    bool hit = false;
    float dx = ax - bx, dy = ay - by;
    float ra = 0.5f * sqrtf(al * al + aw * aw);
    float rb = 0.5f * sqrtf(bl * bl + bw * bw);
    float top = fminf(az + 0.5f * ah, bz + 0.5f * bh);
    float bot = fmaxf(az - 0.5f * ah, bz - 0.5f * bh);
    float hov = fmaxf(top - bot, 0.0f);
    float rr = ra + rb;
    // Exact reject: disjoint circumscribed circles or no height overlap => iou = 0.
    if (dx * dx + dy * dy <= rr * rr && hov > 0.0f) {
        float ca = cosf(tha), sa = sinf(tha);
        float cb = cosf(thb), sb = sinf(thb);

        float px[8], py[8];
        {   // corners of A: signs (0.5,-0.5),(0.5,0.5),(-0.5,0.5),(-0.5,-0.5)
            float hx = 0.5f * al, hy = 0.5f * aw;
            float sxv[4] = { hx, hx, -hx, -hx };
            float syv[4] = { -hy, hy, hy, -hy };
#pragma unroll
            for (int k = 0; k < 4; ++k) {
                px[k] = sxv[k] * ca - syv[k] * sa + ax;
                py[k] = sxv[k] * sa + syv[k] * ca + ay;
            }
#pragma unroll
            for (int k = 4; k < 8; ++k) { px[k] = 0.0f; py[k] = 0.0f; }
        }
        float qx[4], qy[4];
        {
            float hx = 0.5f * bl, hy = 0.5f * bw;
            float sxv[4] = { hx, hx, -hx, -hx };
            float syv[4] = { -hy, hy, hy, -hy };
#pragma unroll
            for (int k = 0; k < 4; ++k) {
                qx[k] = sxv[k] * cb - syv[k] * sb + bx;
                qy[k] = sxv[k] * sb + syv[k] * cb + by;
            }
        }
        int cnt = 4;
#pragma unroll
        for (int k = 0; k < 4; ++k)
            clip_edge(px, py, cnt, qx[k], qy[k], qx[(k + 1) & 3], qy[(k + 1) & 3]);

        // shoelace area over cnt vertices
        float s2 = 0.0f;
#pragma unroll
        for (int v = 0; v < 8; ++v) {
            bool valid = v < cnt;
            bool wrap = !(v + 1 < cnt);
            float p2x = wrap ? px[0] : px[(v + 1) & 7];
            float p2y = wrap ? py[0] : py[(v + 1) & 7];
            float cr = px[v] * p2y - p2x * py[v];
            s2 += valid ? cr : 0.0f;
        }
        float area = 0.5f * fabsf(s2);
        float inter = area * hov;
        float va = al * aw * ah, vb = bl * bw * bh;
        float iou = inter / fmaxf(va + vb - inter, 1e-6f);
        hit = iou > IOU_THR_F;
    }
    unsigned long long bal = __ballot(hit);
    if ((threadIdx.x & 63) == 0)
        adj[t >> 6] = bal;
}

// ---------------------------------------------------------------------------
// Kernel 1.5: bit-transpose each adjacency row.
// T[r][l] (u16): bit k = adj(r, 64k + l)  == bit l of natural word k.
// One wave per row; lane l gathers bit l of the row's 16 u64 words.
// ---------------------------------------------------------------------------
__global__ __launch_bounds__(256) void transpose_kernel(const unsigned long long* __restrict__ adj,
                                                        unsigned short* __restrict__ T) {
    int row = (blockIdx.x * 256 + threadIdx.x) >> 6;   // wave-uniform
    row = __builtin_amdgcn_readfirstlane(row);          // force SGPR / s_load path
    int lane = threadIdx.x & 63;
    const unsigned long long* rp = adj + row * 16;
    unsigned int acc = 0;
#pragma unroll
    for (int k = 0; k < 16; ++k) {
        unsigned long long w = rp[k];
        acc |= (unsigned int)((w >> lane) & 1ull) << k;
    }
    T[row * 64 + lane] = (unsigned short)acc;
}

// ---------------------------------------------------------------------------
// Kernel 2: greedy-clustering SEED SCAN only -- fully static straight-line
// serial code on wave 0. No ballots, no branches, no chain-coupled memory.
// Box mapping: box 64g+l <-> lane l, um bit g. Row r = 64*tau + k:
//   seed test: bit tau of lane k's um  -> v_readlane (static k after unroll)
//   update:    um &= ~((0-sd) & T[r][lane])   (branchless, sd uniform 0/1)
//   seq capture: lane k records curv via (lane==k) cndmask  -- off-chain.
// T-rows for each tile are preloaded into an SROA register array with static
// indices (64 ds_read_u16 issued up-front, off the serial chain).
// Seed-order equivalence with reference: unassigned set only loses bits ->
// argmax(unassigned) sequence is strictly increasing -> ordered scan r=0..1023.
// Assignment (last adjacent seed wins, incl. reassignment) deferred to the
// parallel assign_kernel.
// ---------------------------------------------------------------------------
__global__ __launch_bounds__(1024) void scan_kernel(const unsigned long long* __restrict__ T64,
                                                    int* __restrict__ seq,
                                                    int* __restrict__ nclust_out) {
    __shared__ unsigned long long sT64[NBOX * 16];   // 131072 B = 128 KiB
    const unsigned short* sT = (const unsigned short*)sT64;
    int tid = threadIdx.x;
#pragma unroll
    for (int j = 0; j < 16; ++j)
        sT64[j * 1024 + tid] = T64[j * 1024 + tid];
    __syncthreads();
    if (tid >= 64) return;                           // wave 0 scans alone
    int lane = tid;

    unsigned int um = 0xFFFFu;                       // bit g: box 64g+lane unassigned
    int cur = 1;
    for (int tau = 0; tau < 16; ++tau) {
        unsigned short tb[64];                       // static-index only -> SROA to VGPRs
#pragma unroll
        for (int k = 0; k < 64; ++k)
            tb[k] = sT[(tau * 64 + k) * 64 + lane];
        int myseq = 0;
#pragma unroll
        for (int k = 0; k < 64; ++k) {
            int umk = __builtin_amdgcn_readlane((int)um, k);     // uniform
            int sd = (umk >> tau) & 1;                           // uniform 0/1
            unsigned int m = (0u - (unsigned int)sd) & (unsigned int)tb[k];
            um &= ~m;                                            // clears seed's row targets
            int curv = cur & (-sd);                              // sd ? cur : 0 (uniform)
            cur += sd;
            myseq = (lane == k) ? curv : myseq;                  // off-chain capture
        }
        seq[tau * 64 + lane] = myseq;               // lane l holds seq of row tau*64+l
    }
    if (lane == 0)
        *nclust_out = cur - 1;
}

// ---------------------------------------------------------------------------
// Kernel 2.5: parallel cluster-id assignment. Box b = 64*w + l (block w,
// lane l): ci[b] = seq of the LAST seed r adjacent to b (reassignment
// semantics). T16[r*64+l] is a coalesced 128B load; seq[r] is uniform.
// ---------------------------------------------------------------------------
__global__ __launch_bounds__(64) void assign_kernel(const unsigned short* __restrict__ T16,
                                                    const int* __restrict__ seq,
                                                    int* __restrict__ ci) {
    int w = blockIdx.x;          // 0..15
    int lane = threadIdx.x;      // box = w*64 + lane
    int c = 0;
#pragma unroll 8
    for (int r = 0; r < NBOX; ++r) {
        unsigned int t = T16[r * 64 + lane];
        int sq = seq[r];                           // uniform scalar load
        bool hitb = (sq != 0) && (((t >> w) & 1u) != 0u);
        c = hitb ? sq : c;                         // later seeds overwrite
    }
    ci[w * 64 + lane] = c;
}

// ---------------------------------------------------------------------------
// Kernel 3: cluster fusion. Block = 256 threads = 4 waves; wave w handles
// cid = blockIdx*4 + w + 1. Boxes (heading limited), scores, ci in LDS.
// Block-level early exit when all 4 cids exceed n_clusters (block-uniform,
// skips the 36 KB LDS staging); per-wave early exit for empty cids otherwise.
// ---------------------------------------------------------------------------
__global__ __launch_bounds__(256) void fusion_kernel(const float* __restrict__ boxes,
                                                     const float* __restrict__ scores,
                                                     const int* __restrict__ ci,
                                                     const int* __restrict__ nclust_p,
                                                     float* __restrict__ out) {
    __shared__ float sb[NBOX][7];
    __shared__ float ss[NBOX];
    __shared__ int   sc[NBOX];
    int tid = threadIdx.x;
    int nclust = *nclust_p;                       // block-uniform scalar load

    if (blockIdx.x * 4 + 1 > nclust) {            // all 4 cids empty: zero rows, skip staging
        if (tid < 28) {
            out[blockIdx.x * 28 + tid] = 0.0f;    // 4 cids x 7 floats
        }
        return;
    }

    for (int idx = tid; idx < NBOX * 7; idx += 256) {
        float v = boxes[idx];
        int col = idx % 7;
        if (col == 6) v = limit_period_f(v);
        sb[idx / 7][col] = v;
    }
    for (int b = tid; b < NBOX; b += 256) {
        ss[b] = scores[b];
        sc[b] = ci[b];
    }
    __syncthreads();

    int wave = tid >> 6;
    int lane = tid & 63;
    int cid = blockIdx.x * 4 + wave + 1;

    // ---- pass 1: argmax of masked scores (first occurrence on ties) ----
    float bv = -INFINITY;
    int bi = 0;
    for (int c = 0; c < 16; ++c) {
        int b = c * 64 + lane;
        float v = (sc[b] == cid) ? ss[b] : -INFINITY;
        if (v > bv) { bv = v; bi = b; }          // ascending b => keeps first max
    }
#pragma unroll
    for (int off = 32; off > 0; off >>= 1) {
        float ov = __shfl_xor(bv, off);
        int   oi = __shfl_xor(bi, off);
        if (ov > bv || (ov == bv && oi < bi)) { bv = ov; bi = oi; }
    }
    float* o = out + (cid - 1) * 7;
    if (!(bv > -INFINITY)) {                     // empty cluster: all-zero row
        if (lane == 0) {
#pragma unroll
            for (int jj = 0; jj < 7; ++jj) o[jj] = 0.0f;
        }
        return;
    }
    float d0 = sb[bi][6];

    // ---- pass 2: flip decision + score sum ----
    float sgt = 0.0f, sngt = 0.0f, ssum = 0.0f;
    for (int c = 0; c < 16; ++c) {
        int b = c * 64 + lane;
        float s = (sc[b] == cid) ? ss[b] : 0.0f;
        float diff = fabsf(sb[b][6] - d0);
        diff = (diff > PI_F) ? (TWO_PI_F - diff) : diff;
        bool gt = diff > HALF_PI_F;
        sgt += gt ? s : 0.0f;
        sngt += gt ? 0.0f : s;
        ssum += s;
    }
#pragma unroll
    for (int off = 32; off > 0; off >>= 1) {
        sgt  += __shfl_xor(sgt, off);
        sngt += __shfl_xor(sngt, off);
        ssum += __shfl_xor(ssum, off);
    }
    bool flip = (sgt <= sngt);
    float inv = ssum;                            // non-empty => ssum > 0

    // ---- pass 3: weighted sums (sn applied per-box like the reference) ----
    float sint = 0.0f, cost = 0.0f;
    float acc[6] = { 0.0f, 0.0f, 0.0f, 0.0f, 0.0f, 0.0f };
    for (int c = 0; c < 16; ++c) {
        int b = c * 64 + lane;
        float s = (sc[b] == cid) ? ss[b] : 0.0f;
        float sn = s / inv;
        float dH = sb[b][6];
        float diff = fabsf(dH - d0);
        diff = (diff > PI_F) ? (TWO_PI_F - diff) : diff;
        bool gt = diff > HALF_PI_F;
        bool cond = flip ? gt : !gt;
        float dd = cond ? (dH + PI_F) : dH;
        dd = limit_period_f(dd);
        sint += sinf(dd) * sn;
        cost += cosf(dd) * sn;
#pragma unroll
        for (int jj = 0; jj < 6; ++jj)
            acc[jj] += sb[b][jj] * sn;
    }
#pragma unroll
    for (int off = 32; off > 0; off >>= 1) {
        sint += __shfl_xor(sint, off);
        cost += __shfl_xor(cost, off);
#pragma unroll
        for (int jj = 0; jj < 6; ++jj)
            acc[jj] += __shfl_xor(acc[jj], off);
    }

    if (lane == 0) {
#pragma unroll
        for (int jj = 0; jj < 6; ++jj) o[jj] = acc[jj];
        o[6] = atan2f(sint, cost);
    }
}

extern "C" void kernel_launch(void* const* d_in, const int* in_sizes, int n_in,
                              void* d_out, int out_size, void* d_ws, size_t ws_size,
                              hipStream_t stream) {
    const float* boxes  = (const float*)d_in[0];   // (1024,7) f32
    const float* scores = (const float*)d_in[1];   // (1024,)  f32
    // ws layout (256 KiB total, proven available):
    //   [0,128K):   natural adj (live: iou -> transpose). After transpose it is
    //               dead and the region is reused for seq/ci/nclust.
    //   [128K,256K): transposed T (live: transpose -> scan, assign).
    unsigned long long* adj = (unsigned long long*)d_ws;
    unsigned short* T = (unsigned short*)((char*)d_ws + (size_t)NBOX * 16 * 8);
    int* seq    = (int*)d_ws;                          // 4 KiB, aliases dead adj
    int* ci     = (int*)((char*)d_ws + 4096);          // 4 KiB
    int* nclust = (int*)((char*)d_ws + 8192);          // 4 B
    float* out = (float*)d_out;                        // (1024,7) f32

    iou_adj_kernel<<<(NBOX * NBOX) / 256, 256, 0, stream>>>(boxes, adj);
    transpose_kernel<<<NBOX / 4, 256, 0, stream>>>(adj, T);
    scan_kernel<<<1, 1024, 0, stream>>>((const unsigned long long*)T, seq, nclust);
    assign_kernel<<<16, 64, 0, stream>>>(T, seq, ci);
    fusion_kernel<<<NBOX / 4, 256, 0, stream>>>(boxes, scores, ci, nclust, out);
}

// Round 9
// 162.395 us; speedup vs baseline: 2.3733x; 2.3733x over previous
//
#include <hip/hip_runtime.h>
#include <math.h>

#define NBOX 1024
#define PI_F 3.141592653f
#define TWO_PI_F 6.283185306f
#define HALF_PI_F 1.5707963265f
#define IOU_THR_F 0.3f

__device__ __forceinline__ float limit_period_f(float v) {
    return v - floorf(v / TWO_PI_F + 0.5f) * TWO_PI_F;
}

// ---------------------------------------------------------------------------
// Clip polygon (px,py,cnt) by half-plane left of edge (a->b).
// Fully unrolled, register-only (no runtime-indexed array writes).
// ---------------------------------------------------------------------------
__device__ __forceinline__ void clip_edge(float (&px)[8], float (&py)[8], int &cnt,
                                          float axp, float ayp, float bxp, float byp) {
    float ex = bxp - axp, ey = byp - ayp;
    float d[8];
#pragma unroll
    for (int v = 0; v < 8; ++v)
        d[v] = ex * (py[v] - ayp) - ey * (px[v] - axp);

    float cxv[16], cyv[16];
    bool fl[16];
#pragma unroll
    for (int v = 0; v < 8; ++v) {
        bool valid = v < cnt;
        bool wrap = !(v + 1 < cnt);              // reference: nxt = idx+1<cnt ? idx+1 : 0
        float p2x = wrap ? px[0] : px[(v + 1) & 7];
        float p2y = wrap ? py[0] : py[(v + 1) & 7];
        float d2v = wrap ? d[0] : d[(v + 1) & 7];
        float d1v = d[v];
        bool in1 = d1v >= 0.0f, in2 = d2v >= 0.0f;
        fl[2 * v] = in1 && valid;
        cxv[2 * v] = px[v];
        cyv[2 * v] = py[v];
        fl[2 * v + 1] = (in1 != in2) && valid;
        float den = d1v - d2v;
        float t = d1v / (fabsf(den) > 1e-8f ? den : 1.0f);
        cxv[2 * v + 1] = px[v] + t * (p2x - px[v]);
        cyv[2 * v + 1] = py[v] + t * (p2y - py[v]);
    }

    // Compact candidates into output slots with an unrolled select network.
    int pos = 0;
    float ox[8], oy[8];
#pragma unroll
    for (int o = 0; o < 8; ++o) { ox[o] = 0.0f; oy[o] = 0.0f; }
#pragma unroll
    for (int c = 0; c < 16; ++c) {
#pragma unroll
        for (int o = 0; o < 8; ++o) {
            if (o > c) continue;                 // pos[c] <= c, compile-time prune
            if (fl[c] && pos == o) { ox[o] = cxv[c]; oy[o] = cyv[c]; }
        }
        pos += fl[c] ? 1 : 0;
    }
    cnt = pos > 8 ? 8 : pos;
#pragma unroll
    for (int v = 0; v < 8; ++v) { px[v] = ox[v]; py[v] = oy[v]; }
}

// ---------------------------------------------------------------------------
// Kernel 1: pairwise IoU3D > 0.3 adjacency bitmask. One thread per (i,j);
// wave = 64 consecutive j for one i -> one u64 adjacency word per wave.
// Natural layout: adj[i*16 + g] bit l = adjacency(i, 64g + l).
// ---------------------------------------------------------------------------
__global__ __launch_bounds__(256) void iou_adj_kernel(const float* __restrict__ boxes,
                                                      unsigned long long* __restrict__ adj) {
    int t = blockIdx.x * 256 + threadIdx.x;
    int i = t >> 10;
    int j = t & 1023;
    const float* ba = boxes + i * 7;
    const float* bb = boxes + j * 7;
    float ax = ba[0], ay = ba[1], az = ba[2], al = ba[3], aw = ba[4], ah = ba[5];
    float bx = bb[0], by = bb[1], bz = bb[2], bl = bb[3], bw = bb[4], bh = bb[5];
    float tha = limit_period_f(ba[6]);
    float thb = limit_period_f(bb[6]);

    bool hit = false;
    float dx = ax - bx, dy = ay - by;
    float ra = 0.5f * sqrtf(al * al + aw * aw);
    float rb = 0.5f * sqrtf(bl * bl + bw * bw);
    float top = fminf(az + 0.5f * ah, bz + 0.5f * bh);
    float bot = fmaxf(az - 0.5f * ah, bz - 0.5f * bh);
    float hov = fmaxf(top - bot, 0.0f);
    float rr = ra + rb;
    // Exact reject: disjoint circumscribed circles or no height overlap => iou = 0.
    if (dx * dx + dy * dy <= rr * rr && hov > 0.0f) {
        float ca = cosf(tha), sa = sinf(tha);
        float cb = cosf(thb), sb = sinf(thb);

        float px[8], py[8];
        {   // corners of A: signs (0.5,-0.5),(0.5,0.5),(-0.5,0.5),(-0.5,-0.5)
            float hx = 0.5f * al, hy = 0.5f * aw;
            float sxv[4] = { hx, hx, -hx, -hx };
            float syv[4] = { -hy, hy, hy, -hy };
#pragma unroll
            for (int k = 0; k < 4; ++k) {
                px[k] = sxv[k] * ca - syv[k] * sa + ax;
                py[k] = sxv[k] * sa + syv[k] * ca + ay;
            }
#pragma unroll
            for (int k = 4; k < 8; ++k) { px[k] = 0.0f; py[k] = 0.0f; }
        }
        float qx[4], qy[4];
        {
            float hx = 0.5f * bl, hy = 0.5f * bw;
            float sxv[4] = { hx, hx, -hx, -hx };
            float syv[4] = { -hy, hy, hy, -hy };
#pragma unroll
            for (int k = 0; k < 4; ++k) {
                qx[k] = sxv[k] * cb - syv[k] * sb + bx;
                qy[k] = sxv[k] * sb + syv[k] * cb + by;
            }
        }
        int cnt = 4;
#pragma unroll
        for (int k = 0; k < 4; ++k)
            clip_edge(px, py, cnt, qx[k], qy[k], qx[(k + 1) & 3], qy[(k + 1) & 3]);

        // shoelace area over cnt vertices
        float s2 = 0.0f;
#pragma unroll
        for (int v = 0; v < 8; ++v) {
            bool valid = v < cnt;
            bool wrap = !(v + 1 < cnt);
            float p2x = wrap ? px[0] : px[(v + 1) & 7];
            float p2y = wrap ? py[0] : py[(v + 1) & 7];
            float cr = px[v] * p2y - p2x * py[v];
            s2 += valid ? cr : 0.0f;
        }
        float area = 0.5f * fabsf(s2);
        float inter = area * hov;
        float va = al * aw * ah, vb = bl * bw * bh;
        float iou = inter / fmaxf(va + vb - inter, 1e-6f);
        hit = iou > IOU_THR_F;
    }
    unsigned long long bal = __ballot(hit);
    if ((threadIdx.x & 63) == 0)
        adj[t >> 6] = bal;
}

// ---------------------------------------------------------------------------
// Kernel 1.5: bit-transpose each adjacency row.
// T[r][l] (u16): bit k = adj(r, 64k + l)  == bit l of natural word k.
// One wave per row; lane l gathers bit l of the row's 16 u64 words.
// ---------------------------------------------------------------------------
__global__ __launch_bounds__(256) void transpose_kernel(const unsigned long long* __restrict__ adj,
                                                        unsigned short* __restrict__ T) {
    int row = (blockIdx.x * 256 + threadIdx.x) >> 6;   // wave-uniform
    row = __builtin_amdgcn_readfirstlane(row);          // force SGPR / s_load path
    int lane = threadIdx.x & 63;
    const unsigned long long* rp = adj + row * 16;
    unsigned int acc = 0;
#pragma unroll
    for (int k = 0; k < 16; ++k) {
        unsigned long long w = rp[k];
        acc |= (unsigned int)((w >> lane) & 1ull) << k;
    }
    T[row * 64 + lane] = (unsigned short)acc;
}

// ---------------------------------------------------------------------------
// Kernel 2: greedy clustering = scan + in-kernel parallel assignment.
// Phase A (wave 0): fully static straight-line seed scan -- no ballots, no
//   branches, no chain-coupled memory (R8 evidence: this structure left the
//   top-5). seq values are recorded to LDS (4 KB).
// Phase B (all 16 waves): ci[b] = max over rows r adjacent to b of seq[r]
//   (seq strictly increases over seeds => max == "last seed wins" ==
//   reference's reassignment semantics). Wave w covers rows 64w..64w+63;
//   lane l owns box column l; bit g of sT[r][l] tests box 64g+l. Partial
//   maxes tree-reduce via 4 KB LDS; wave 0 writes ci.
// R8 lesson: the standalone assign kernel was 257us (VGPR=4, 16 waves
// chip-wide, 1024 latency-serialized global loads each). Here the same
// reduction runs from LDS with 16 waves resident and 64 iters/wave.
// LDS: 128K (sT) + 4K (sseq) + 4K (part) = 136K <= 160K.
// ---------------------------------------------------------------------------
__global__ __launch_bounds__(1024) void cluster_kernel(const unsigned long long* __restrict__ T64,
                                                       int* __restrict__ ci,
                                                       int* __restrict__ nclust_out) {
    __shared__ unsigned long long sT64[NBOX * 16];   // 131072 B = 128 KiB
    __shared__ int sseq[NBOX];                       // 4 KiB
    __shared__ int part[16][64];                     // 4 KiB
    const unsigned short* sT = (const unsigned short*)sT64;
    int tid = threadIdx.x;
#pragma unroll
    for (int j = 0; j < 16; ++j)
        sT64[j * 1024 + tid] = T64[j * 1024 + tid];
    __syncthreads();

    int wid = tid >> 6;
    int lane = tid & 63;

    // ---- Phase A: serial seed scan on wave 0 ----
    if (wid == 0) {
        unsigned int um = 0xFFFFu;                   // bit g: box 64g+lane unassigned
        int cur = 1;
        for (int tau = 0; tau < 16; ++tau) {
            unsigned short tb[64];                   // static-index only -> SROA to VGPRs
#pragma unroll
            for (int k = 0; k < 64; ++k)
                tb[k] = sT[(tau * 64 + k) * 64 + lane];
            int myseq = 0;
#pragma unroll
            for (int k = 0; k < 64; ++k) {
                int umk = __builtin_amdgcn_readlane((int)um, k);     // uniform
                int sd = (umk >> tau) & 1;                           // uniform 0/1
                unsigned int m = (0u - (unsigned int)sd) & (unsigned int)tb[k];
                um &= ~m;                                            // clears seed's row targets
                int curv = cur & (-sd);                              // sd ? cur : 0 (uniform)
                cur += sd;
                myseq = (lane == k) ? curv : myseq;                  // off-chain capture
            }
            sseq[tau * 64 + lane] = myseq;          // lane l: seq of row tau*64+l
        }
        if (lane == 0)
            *nclust_out = cur - 1;
    }
    __syncthreads();

    // ---- Phase B: parallel assignment (max-reduction over rows) ----
    int c = 0;
    int rbase = wid * 64;
#pragma unroll 8
    for (int d = 0; d < 64; ++d) {
        int r = rbase + d;
        unsigned int t = sT[r * 64 + lane];          // 128B row, 2-way bank alias (free)
        int sq = sseq[r];                            // same-address broadcast
        // lane l's candidate for box 64g+l is (bit g set && sq): evaluated per g below
#pragma unroll
        for (int g = 0; g < 1; ++g) { }              // (placeholder: per-wave single g pass below)
        // Each wave must cover ALL 16 box groups for its rows:
        // c is per (box group) -- restructure: accumulate 16 per-lane maxes.
        (void)t; (void)sq;
        break;
    }
    // NOTE: restructured below -- each wave covers its 64 rows for ALL 16
    // groups, keeping 16 running maxes in registers (static array -> SROA).
    int cg[16];
#pragma unroll
    for (int g = 0; g < 16; ++g) cg[g] = 0;
#pragma unroll 4
    for (int d = 0; d < 64; ++d) {
        int r = rbase + d;
        unsigned int t = sT[r * 64 + lane];
        int sq = sseq[r];
#pragma unroll
        for (int g = 0; g < 16; ++g) {
            bool hitb = ((t >> g) & 1u) != 0u;
            cg[g] = (hitb && sq > cg[g]) ? sq : cg[g];
        }
    }
    // Reduce across the 16 waves, one box group at a time.
#pragma unroll
    for (int g = 0; g < 16; ++g) {
        part[wid][lane] = cg[g];
        __syncthreads();
        if (wid == 0) {
            int m = part[0][lane];
#pragma unroll
            for (int w = 1; w < 16; ++w) m = m > part[w][lane] ? m : part[w][lane];
            ci[g * 64 + lane] = m;
        }
        __syncthreads();
    }
}

// ---------------------------------------------------------------------------
// Kernel 3: cluster fusion. Block = 256 threads = 4 waves; wave w handles
// cid = blockIdx*4 + w + 1. Boxes (heading limited), scores, ci in LDS.
// Block-level early exit when all 4 cids exceed n_clusters (block-uniform,
// skips the 36 KB LDS staging); per-wave early exit for empty cids otherwise.
// ---------------------------------------------------------------------------
__global__ __launch_bounds__(256) void fusion_kernel(const float* __restrict__ boxes,
                                                     const float* __restrict__ scores,
                                                     const int* __restrict__ ci,
                                                     const int* __restrict__ nclust_p,
                                                     float* __restrict__ out) {
    __shared__ float sb[NBOX][7];
    __shared__ float ss[NBOX];
    __shared__ int   sc[NBOX];
    int tid = threadIdx.x;
    int nclust = *nclust_p;                       // block-uniform scalar load

    if (blockIdx.x * 4 + 1 > nclust) {            // all 4 cids empty: zero rows, skip staging
        if (tid < 28) {
            out[blockIdx.x * 28 + tid] = 0.0f;    // 4 cids x 7 floats
        }
        return;
    }

    for (int idx = tid; idx < NBOX * 7; idx += 256) {
        float v = boxes[idx];
        int col = idx % 7;
        if (col == 6) v = limit_period_f(v);
        sb[idx / 7][col] = v;
    }
    for (int b = tid; b < NBOX; b += 256) {
        ss[b] = scores[b];
        sc[b] = ci[b];
    }
    __syncthreads();

    int wave = tid >> 6;
    int lane = tid & 63;
    int cid = blockIdx.x * 4 + wave + 1;

    // ---- pass 1: argmax of masked scores (first occurrence on ties) ----
    float bv = -INFINITY;
    int bi = 0;
    for (int c = 0; c < 16; ++c) {
        int b = c * 64 + lane;
        float v = (sc[b] == cid) ? ss[b] : -INFINITY;
        if (v > bv) { bv = v; bi = b; }          // ascending b => keeps first max
    }
#pragma unroll
    for (int off = 32; off > 0; off >>= 1) {
        float ov = __shfl_xor(bv, off);
        int   oi = __shfl_xor(bi, off);
        if (ov > bv || (ov == bv && oi < bi)) { bv = ov; bi = oi; }
    }
    float* o = out + (cid - 1) * 7;
    if (!(bv > -INFINITY)) {                     // empty cluster: all-zero row
        if (lane == 0) {
#pragma unroll
            for (int jj = 0; jj < 7; ++jj) o[jj] = 0.0f;
        }
        return;
    }
    float d0 = sb[bi][6];

    // ---- pass 2: flip decision + score sum ----
    float sgt = 0.0f, sngt = 0.0f, ssum = 0.0f;
    for (int c = 0; c < 16; ++c) {
        int b = c * 64 + lane;
        float s = (sc[b] == cid) ? ss[b] : 0.0f;
        float diff = fabsf(sb[b][6] - d0);
        diff = (diff > PI_F) ? (TWO_PI_F - diff) : diff;
        bool gt = diff > HALF_PI_F;
        sgt += gt ? s : 0.0f;
        sngt += gt ? 0.0f : s;
        ssum += s;
    }
#pragma unroll
    for (int off = 32; off > 0; off >>= 1) {
        sgt  += __shfl_xor(sgt, off);
        sngt += __shfl_xor(sngt, off);
        ssum += __shfl_xor(ssum, off);
    }
    bool flip = (sgt <= sngt);
    float inv = ssum;                            // non-empty => ssum > 0

    // ---- pass 3: weighted sums (sn applied per-box like the reference) ----
    float sint = 0.0f, cost = 0.0f;
    float acc[6] = { 0.0f, 0.0f, 0.0f, 0.0f, 0.0f, 0.0f };
    for (int c = 0; c < 16; ++c) {
        int b = c * 64 + lane;
        float s = (sc[b] == cid) ? ss[b] : 0.0f;
        float sn = s / inv;
        float dH = sb[b][6];
        float diff = fabsf(dH - d0);
        diff = (diff > PI_F) ? (TWO_PI_F - diff) : diff;
        bool gt = diff > HALF_PI_F;
        bool cond = flip ? gt : !gt;
        float dd = cond ? (dH + PI_F) : dH;
        dd = limit_period_f(dd);
        sint += sinf(dd) * sn;
        cost += cosf(dd) * sn;
#pragma unroll
        for (int jj = 0; jj < 6; ++jj)
            acc[jj] += sb[b][jj] * sn;
    }
#pragma unroll
    for (int off = 32; off > 0; off >>= 1) {
        sint += __shfl_xor(sint, off);
        cost += __shfl_xor(cost, off);
#pragma unroll
        for (int jj = 0; jj < 6; ++jj)
            acc[jj] += __shfl_xor(acc[jj], off);
    }

    if (lane == 0) {
#pragma unroll
        for (int jj = 0; jj < 6; ++jj) o[jj] = acc[jj];
        o[6] = atan2f(sint, cost);
    }
}

extern "C" void kernel_launch(void* const* d_in, const int* in_sizes, int n_in,
                              void* d_out, int out_size, void* d_ws, size_t ws_size,
                              hipStream_t stream) {
    const float* boxes  = (const float*)d_in[0];   // (1024,7) f32
    const float* scores = (const float*)d_in[1];   // (1024,)  f32
    // ws layout (256 KiB + 8 KiB, proven available):
    //   [0,128K):   natural adj (live: iou -> transpose); dead after transpose,
    //               reused for ci/nclust.
    //   [128K,256K): transposed T (live: transpose -> cluster).
    unsigned long long* adj = (unsigned long long*)d_ws;
    unsigned short* T = (unsigned short*)((char*)d_ws + (size_t)NBOX * 16 * 8);
    int* ci     = (int*)d_ws;                          // 4 KiB, aliases dead adj
    int* nclust = (int*)((char*)d_ws + 4096);          // 4 B
    float* out = (float*)d_out;                        // (1024,7) f32

    iou_adj_kernel<<<(NBOX * NBOX) / 256, 256, 0, stream>>>(boxes, adj);
    transpose_kernel<<<NBOX / 4, 256, 0, stream>>>(adj, T);
    cluster_kernel<<<1, 1024, 0, stream>>>((const unsigned long long*)T, ci, nclust);
    fusion_kernel<<<NBOX / 4, 256, 0, stream>>>(boxes, scores, ci, nclust, out);
}